// Round 1
// baseline (442.877 us; speedup 1.0000x reference)
//
#include <hip/hip_runtime.h>
#include <stdint.h>

// B=4, N=M=4096, C=256
#define CAP 192   // max matches kept per row (lambda~10, Poisson tail => never hit)

typedef __attribute__((ext_vector_type(4))) float f32x4;
typedef __attribute__((ext_vector_type(8))) short bf16x8;

__device__ __forceinline__ float bf2f(ushort u) {
  return __uint_as_float(((unsigned)u) << 16);
}
__device__ __forceinline__ ushort f2bf(float f) {
  unsigned u = __float_as_uint(f);
  return (ushort)((u + 0x7fffu + ((u >> 16) & 1u)) >> 16);  // RNE
}
__device__ __forceinline__ float wredsum(float v) {
#pragma unroll
  for (int o = 32; o; o >>= 1) v += __shfl_xor(v, o);
  return v;
}

// ---------------- f32 -> bf16 converts ----------------
__global__ __launch_bounds__(256) void cvt_kernel(const float* __restrict__ s,
                                                  ushort* __restrict__ d, int n4) {
  int i = blockIdx.x * 256 + threadIdx.x;
  if (i < n4) {
    float4 v = *(const float4*)(s + (size_t)i * 4);
    ushort4 o = { f2bf(v.x), f2bf(v.y), f2bf(v.z), f2bf(v.w) };
    *(ushort4*)(d + (size_t)i * 4) = o;
  }
}

__global__ __launch_bounds__(256) void cvt4_kernel(
    const float* __restrict__ s0, const float* __restrict__ s1,
    const float* __restrict__ s2, const float* __restrict__ s3,
    ushort* __restrict__ d0, ushort* __restrict__ d1,
    ushort* __restrict__ d2, ushort* __restrict__ d3) {
  int seg = blockIdx.x >> 6;  // 64 blocks per 65536-elem segment
  int i = ((blockIdx.x & 63) * 256 + threadIdx.x) * 4;
  const float* s = (seg == 0) ? s0 : (seg == 1) ? s1 : (seg == 2) ? s2 : s3;
  ushort* d = (seg == 0) ? d0 : (seg == 1) ? d1 : (seg == 2) ? d2 : d3;
  float4 v = *(const float4*)(s + i);
  ushort4 o = { f2bf(v.x), f2bf(v.y), f2bf(v.z), f2bf(v.w) };
  *(ushort4*)(d + i) = o;
}

// ---------------- GEMM: Y[r,o] = sum_c A[r,c]*W[o,c] + bias[o] ----------------
// A bf16 [R,256], W bf16 [256,256] (row-major [out,in]), OutT = ushort(bf16) or float
template <typename OutT>
__global__ __launch_bounds__(256, 2) void gemm_bt(const ushort* __restrict__ A,
                                                  const ushort* __restrict__ W,
                                                  const float* __restrict__ bias,
                                                  OutT* __restrict__ Y, int R) {
  __shared__ __align__(16) ushort As[128 * 32];
  __shared__ __align__(16) ushort Bs[128 * 32];
  int tid = threadIdx.x;
  int lane = tid & 63, wid = tid >> 6;
  int bm = blockIdx.x >> 1, bn = blockIdx.x & 1;
  int r0 = bm * 128, c0 = bn * 128;
  int wr = wid >> 1, wc = wid & 1;
  f32x4 acc[4][4] = {};
  for (int k0 = 0; k0 < 256; k0 += 32) {
    __syncthreads();
#pragma unroll
    for (int p = 0; p < 2; ++p) {
      int u = p * 2048 + tid * 8;
      int row = u >> 5, col = u & 31;
      *(bf16x8*)&As[u] = *(const bf16x8*)(A + (size_t)(r0 + row) * 256 + k0 + col);
      *(bf16x8*)&Bs[u] = *(const bf16x8*)(W + (size_t)(c0 + row) * 256 + k0 + col);
    }
    __syncthreads();
    bf16x8 af[4], bfr[4];
    int rsel = lane & 15, ksel = (lane >> 4) * 8;
#pragma unroll
    for (int m = 0; m < 4; ++m)
      af[m] = *(bf16x8*)&As[(wr * 64 + m * 16 + rsel) * 32 + ksel];
#pragma unroll
    for (int n = 0; n < 4; ++n)
      bfr[n] = *(bf16x8*)&Bs[(wc * 64 + n * 16 + rsel) * 32 + ksel];
#pragma unroll
    for (int m = 0; m < 4; ++m)
#pragma unroll
      for (int n = 0; n < 4; ++n)
        acc[m][n] = __builtin_amdgcn_mfma_f32_16x16x32_bf16(af[m], bfr[n], acc[m][n], 0, 0, 0);
  }
  int rbase = r0 + wr * 64 + ((lane >> 4) * 4);
  int cbase = c0 + wc * 64 + (lane & 15);
#pragma unroll
  for (int n = 0; n < 4; ++n) {
    float bv = bias[cbase + n * 16];
#pragma unroll
    for (int m = 0; m < 4; ++m) {
#pragma unroll
      for (int j = 0; j < 4; ++j) {
        float v = acc[m][n][j] + bv;
        size_t idx = (size_t)(rbase + m * 16 + j) * 256 + (cbase + n * 16);
        if constexpr (sizeof(OutT) == 2) Y[idx] = (OutT)f2bf(v);
        else Y[idx] = (OutT)v;
      }
    }
  }
}

// ---------------- per-batch sums for fully-masked rows ----------------
__global__ __launch_bounds__(256) void batch_stats(const float* __restrict__ kptsR,
                                                   const ushort* __restrict__ Vb,
                                                   float* __restrict__ sum_uR,
                                                   float* __restrict__ sumV) {
  int b = blockIdx.x >> 4;
  int m0 = (blockIdx.x & 15) * 256;
  int c = threadIdx.x;
  float s = 0.f;
  for (int mm = 0; mm < 256; ++mm)
    s += bf2f(Vb[((size_t)(b * 4096 + m0 + mm)) * 256 + c]);
  atomicAdd(&sumV[b * 256 + c], s);
  float su = kptsR[((size_t)(b * 4096 + m0 + threadIdx.x)) * 2];
  su = wredsum(su);
  __shared__ float red[4];
  if ((threadIdx.x & 63) == 0) red[threadIdx.x >> 6] = su;
  __syncthreads();
  if (threadIdx.x == 0) atomicAdd(&sum_uR[b], red[0] + red[1] + red[2] + red[3]);
}

// ---------------- wave-per-row sparse attention ----------------
__global__ __launch_bounds__(512, 2) void attn_rows(
    const float* __restrict__ kptsL, const float* __restrict__ kptsR,
    const ushort* __restrict__ Qb, const ushort* __restrict__ Kb,
    const ushort* __restrict__ Vb, const float* __restrict__ sum_uR,
    const float* __restrict__ sumV, float* __restrict__ disp_out,
    float* __restrict__ conf_out, ushort* __restrict__ matched,
    int* __restrict__ rowcnt, int2* __restrict__ rowlist) {
  __shared__ float2 kR[4096];
  __shared__ int bufM[8][CAP];
  __shared__ float bufD[8][CAP];
  __shared__ float bufS[8][CAP];
  int tid = threadIdx.x, lane = tid & 63, wid = tid >> 6;
  int b = blockIdx.x >> 9;
  int n = ((blockIdx.x & 511) << 3) + wid;
  int row = (b << 12) + n;
  const float2* kRsrc = (const float2*)kptsR + (size_t)b * 4096;
  for (int i = tid; i < 4096; i += 512) kR[i] = kRsrc[i];
  __syncthreads();
  float2 kL = ((const float2*)kptsL)[(size_t)b * 4096 + n];
  ushort4 qv = *(const ushort4*)(Qb + (size_t)row * 256 + lane * 4);
  float q0 = bf2f(qv.x), q1 = bf2f(qv.y), q2 = bf2f(qv.z), q3 = bf2f(qv.w);
  int cnt = 0;
  for (int m0 = 0; m0 < 4096; m0 += 64) {
    float2 kr = kR[m0 + lane];
    float dv = fabsf(kL.y - kr.y);
    float du = kL.x - kr.x;
    bool hit = (dv < 3.0f) && (du > 0.0f) && (du < 192.0f);
    unsigned long long bal = __ballot(hit);
    while (bal) {
      int src = __ffsll((unsigned long long)bal) - 1;
      bal &= bal - 1;
      float dus = __shfl(du, src);
      if (cnt < CAP) {
        if (lane == 0) { bufM[wid][cnt] = m0 + src; bufD[wid][cnt] = dus; }
        cnt++;
      }
    }
  }
  float conf, disp;
  if (cnt == 0) {
    conf = 0.f;
    disp = kL.x - sum_uR[b] * (1.f / 4096.f);
    float v0 = sumV[b * 256 + lane * 4 + 0] * (1.f / 4096.f);
    float v1 = sumV[b * 256 + lane * 4 + 1] * (1.f / 4096.f);
    float v2 = sumV[b * 256 + lane * 4 + 2] * (1.f / 4096.f);
    float v3 = sumV[b * 256 + lane * 4 + 3] * (1.f / 4096.f);
    if (lane == 0) rowcnt[row] = 0;
    ushort4 st = { f2bf(v0), f2bf(v1), f2bf(v2), f2bf(v3) };
    *(ushort4*)(matched + (size_t)row * 256 + lane * 4) = st;
  } else {
    float mx = -1e30f;
    for (int i = 0; i < cnt; ++i) {
      int m = bufM[wid][i];  // LDS broadcast
      ushort4 kv = *(const ushort4*)(Kb + ((size_t)(b * 4096 + m)) * 256 + lane * 4);
      float p = q0 * bf2f(kv.x) + q1 * bf2f(kv.y) + q2 * bf2f(kv.z) + q3 * bf2f(kv.w);
      p = wredsum(p);
      float s = p * 0.0625f;  // / sqrt(256)
      if (lane == 0) bufS[wid][i] = s;
      mx = fmaxf(mx, s);
    }
    float psum = 0.f, pdisp = 0.f;
    for (int i = lane; i < cnt; i += 64) {
      float e = expf(bufS[wid][i] - mx);
      bufS[wid][i] = e;
      psum += e;
      pdisp += e * bufD[wid][i];
    }
    psum = wredsum(psum);
    pdisp = wredsum(pdisp);
    float inv = 1.f / psum;
    disp = pdisp * inv;
    conf = 1.f;
    for (int i = lane; i < cnt; i += 64) {
      int2 e;
      e.x = bufM[wid][i];
      e.y = __float_as_int(bufS[wid][i] * inv);
      rowlist[(size_t)row * CAP + i] = e;
    }
    if (lane == 0) rowcnt[row] = cnt;
    float a0 = 0, a1 = 0, a2 = 0, a3 = 0;
    for (int i = 0; i < cnt; ++i) {
      float w = bufS[wid][i] * inv;  // broadcast
      int m = bufM[wid][i];
      ushort4 vv = *(const ushort4*)(Vb + ((size_t)(b * 4096 + m)) * 256 + lane * 4);
      a0 += w * bf2f(vv.x); a1 += w * bf2f(vv.y);
      a2 += w * bf2f(vv.z); a3 += w * bf2f(vv.w);
    }
    ushort4 st = { f2bf(a0), f2bf(a1), f2bf(a2), f2bf(a3) };
    *(ushort4*)(matched + (size_t)row * 256 + lane * 4) = st;
  }
  if (lane == 0) { disp_out[row] = disp; conf_out[row] = conf; }
}

// ---------------- attn_weights fill + sparse scatter ----------------
__global__ __launch_bounds__(256) void fill_attn(const int* __restrict__ rowcnt,
                                                 const int2* __restrict__ rowlist,
                                                 float* __restrict__ attn) {
  __shared__ __align__(16) float rowbuf[4096];
  int row = blockIdx.x, tid = threadIdx.x;
  int cnt = rowcnt[row];
  float fill = (cnt == 0) ? (1.f / 4096.f) : 0.f;
  float4* rb4 = (float4*)rowbuf;
  float4 fv = make_float4(fill, fill, fill, fill);
#pragma unroll
  for (int j = 0; j < 4; ++j) rb4[j * 256 + tid] = fv;
  __syncthreads();
  for (int i = tid; i < cnt; i += 256) {
    int2 e = rowlist[(size_t)row * CAP + i];
    rowbuf[e.x] = __int_as_float(e.y);
  }
  __syncthreads();
  float4* dst = (float4*)(attn + (size_t)row * 4096);
#pragma unroll
  for (int j = 0; j < 4; ++j) dst[j * 256 + tid] = rb4[j * 256 + tid];
}

extern "C" void kernel_launch(void* const* d_in, const int* in_sizes, int n_in,
                              void* d_out, int out_size, void* d_ws, size_t ws_size,
                              hipStream_t stream) {
  const float* nodes_L = (const float*)d_in[0];
  const float* nodes_R = (const float*)d_in[1];
  const float* kpts_L = (const float*)d_in[2];
  const float* kpts_R = (const float*)d_in[3];
  const float* Wq = (const float*)d_in[4];
  const float* bq = (const float*)d_in[5];
  const float* Wk = (const float*)d_in[6];
  const float* bk = (const float*)d_in[7];
  const float* Wv = (const float*)d_in[8];
  const float* bv = (const float*)d_in[9];
  const float* Wm = (const float*)d_in[10];
  const float* bm = (const float*)d_in[11];

  float* out = (float*)d_out;            // [4,4096,256]
  float* disp = out + 4194304;           // [4,4096,1]
  float* conf = disp + 16384;            // [4,4096,1]
  float* attn = conf + 16384;            // [4,4096,4096]

  char* ws = (char*)d_ws;
  ushort* Xl = (ushort*)(ws + 0);                 // 8 MB
  ushort* Xr = (ushort*)(ws + 8388608);           // 8 MB
  ushort* Wqb = (ushort*)(ws + 16777216);
  ushort* Wkb = Wqb + 65536;
  ushort* Wvb = Wkb + 65536;
  ushort* Wmb = Wvb + 65536;
  ushort* Qb = (ushort*)(ws + 17301504);          // 8 MB
  ushort* Kb = (ushort*)(ws + 25690112);          // 8 MB
  ushort* Vb = (ushort*)(ws + 34078720);          // 8 MB
  ushort* matched = (ushort*)(ws + 42467328);     // 8 MB
  float* sum_uR = (float*)(ws + 50855936);        // 16 f32
  float* sumV = sum_uR + 16;                      // 1024 f32
  int* rowcnt = (int*)(ws + 50864128);            // 64 KB
  int2* rowlist = (int2*)(ws + 50929664);         // 24 MB

  hipMemsetAsync(sum_uR, 0, (16 + 1024) * 4, stream);
  cvt_kernel<<<4096, 256, 0, stream>>>(nodes_L, Xl, 1048576);
  cvt_kernel<<<4096, 256, 0, stream>>>(nodes_R, Xr, 1048576);
  cvt4_kernel<<<256, 256, 0, stream>>>(Wq, Wk, Wv, Wm, Wqb, Wkb, Wvb, Wmb);
  gemm_bt<ushort><<<256, 256, 0, stream>>>(Xl, Wqb, bq, Qb, 16384);
  gemm_bt<ushort><<<256, 256, 0, stream>>>(Xr, Wkb, bk, Kb, 16384);
  gemm_bt<ushort><<<256, 256, 0, stream>>>(Xr, Wvb, bv, Vb, 16384);
  batch_stats<<<64, 256, 0, stream>>>(kpts_R, Vb, sum_uR, sumV);
  attn_rows<<<2048, 512, 0, stream>>>(kpts_L, kpts_R, Qb, Kb, Vb, sum_uR, sumV,
                                      disp, conf, matched, rowcnt, rowlist);
  fill_attn<<<16384, 256, 0, stream>>>(rowcnt, rowlist, attn);
  gemm_bt<float><<<256, 256, 0, stream>>>(matched, Wmb, bm, out, 16384);
}